// Round 16
// baseline (2184.199 us; speedup 1.0000x reference)
//
#include <hip/hip_runtime.h>

// LSTMFromEmbeddings: B=128, T=1024, E=256, H=256, C=2, bidirectional + meanpool + linear.
//
// R15 = R14 with 256-thread wgs (4 waves, 1 wave/SIMD, 512-VGPR budget): each wave owns
// 4 row-tiles (weights 256 VGPR in-reg), so B-operand LDS reads are shared across 4
// tiles -> per-CU ds_read_b128 traffic HALVED (the largest pipe cost at R14).
// Row-permutation sigma: tile T=4w+i, D-quad l4 -> unit = 16w + 4*l4 + i => each lane's
// 4 units are CONSECUTIVE -> 2 coalesced publish words, own-HS b64 write.
// Sync protocol (tagged parity words, late poll, batched retry, 1 lgkm barrier/step)
// byte-identical to the passing R13/R14.
//  rec: 64 wgs = 16 groups (2 dir x 8 batch-blocks of 16) x 4 members (64 units).
//  prep: bf16(x*mask) image in LDS-tile layout (rotation swizzle pre-applied).
//  head: out = (hsum/1024) @ W_lin^T + b_lin.

#define B_ 128
#define T_ 1024
#define E_ 256
#define H_ 256

typedef short short8 __attribute__((ext_vector_type(8)));
typedef float f32x4 __attribute__((ext_vector_type(4)));
typedef float f32x2 __attribute__((ext_vector_type(2)));

__device__ __forceinline__ unsigned short f2bf(float f) {
  unsigned u = __builtin_bit_cast(unsigned, f);
  u += 0x7fffu + ((u >> 16) & 1u);  // RNE
  return (unsigned short)(u >> 16);
}
__device__ __forceinline__ f32x4 mfma16(short8 a, short8 b, f32x4 c) {
  return __builtin_amdgcn_mfma_f32_16x16x32_bf16(a, b, c, 0, 0, 0);
}
__device__ __forceinline__ float rcpf(float x) { return __builtin_amdgcn_rcpf(x); }

// proven R8 elementwise: 5 exp + 3 rcp per unit
__device__ __forceinline__ float lstm_ew(float gi, float gf, float gg, float go, float& c) {
  float ei = __expf(-gi), ef = __expf(-gf), eg = __expf(-2.f * gg);
  float di = 1.f + ei, df = 1.f + ef, dg = 1.f + eg;
  float r1 = rcpf(di * dg);
  float si = r1 * dg;
  float tg = 2.f * (r1 * di) - 1.f;
  c = rcpf(df) * c + si * tg;
  float eo = __expf(-go), ec = __expf(2.f * c);
  float do_ = 1.f + eo, dc = 1.f + ec;
  float r3 = rcpf(do_ * dc);
  float so = r3 * dc;
  float th = 1.f - 2.f * (r3 * do_);
  return so * th;
}

__device__ __forceinline__ short8 cvt8(f32x4 v0, f32x4 v1) {
  short8 o;
  o[0] = (short)f2bf(v0[0]); o[1] = (short)f2bf(v0[1]);
  o[2] = (short)f2bf(v0[2]); o[3] = (short)f2bf(v0[3]);
  o[4] = (short)f2bf(v1[0]); o[5] = (short)f2bf(v1[1]);
  o[6] = (short)f2bf(v1[2]); o[7] = (short)f2bf(v1[3]);
  return o;
}

__device__ __forceinline__ void bar_lds() {  // LDS-only barrier; vmem stays in flight
  asm volatile("s_waitcnt lgkmcnt(0)" ::: "memory");
  __builtin_amdgcn_s_barrier();
}

__device__ __forceinline__ void gload16(const void* g, void* l) {
  __builtin_amdgcn_global_load_lds(
      (const __attribute__((address_space(1))) void*)g,
      (__attribute__((address_space(3))) void*)l, 16, 0, 0);
}

// ---------------- prep: x image in LDS-tile layout (rotation swizzle) --------
// word gid = (bblk*1024 + t)*512 + r*32 + s; slot s holds chunk (s - r) & 31.
__global__ __launch_bounds__(256, 4) void prep_kernel(
    const float* __restrict__ x, const float* __restrict__ mask,
    unsigned short* __restrict__ img) {
  int gid = blockIdx.x * 256 + threadIdx.x;
  int i = gid & 511;
  int tt = (gid >> 9) & 1023;
  int bblk = gid >> 19;
  int r = i >> 5, s = i & 31, kc = (s - r) & 31;
  int b = bblk * 16 + r;
  const f32x4* src = (const f32x4*)(x + ((size_t)b * T_ + tt) * E_ + kc * 8);
  float mk = mask[(size_t)b * T_ + tt];
  ((short8*)img)[gid] = cvt8(src[0] * mk, src[1] * mk);
}

// step body, compile-time parity PAR: hh reads HS[PAR]; gload -> XS[PAR];
// xg reads XS[1-PAR]; writes HS[1-PAR]; Hbuf parity (1-PAR).
#define REC_STEP(PAR, TT, MORE_)                                                \
  {                                                                             \
    const bool more_ = (MORE_);                                                 \
    if constexpr (PREP) {                                                       \
      if ((TT) + 2 < T_) {                                                      \
        gload16(gsrc, (char*)XS[PAR] + w * 1024);                               \
        gload16(gsrc + 4096, (char*)XS[PAR] + 4096 + w * 1024);                 \
        gsrc += dstep;                                                          \
      }                                                                         \
    }                                                                           \
    f32x4 xva0, xva1, xvb0, xvb1;                                               \
    float mkst = 0.f;                                                           \
    if constexpr (!PREP) {                                                      \
      if (more_) {                                                              \
        int ts = d ? (T_ - 2 - (TT)) : ((TT) + 1);                              \
        const float* xr = x + ((size_t)gb_s * T_ + ts) * E_;                    \
        xva0 = ((const f32x4*)(xr + kc0 * 8))[0];                               \
        xva1 = ((const f32x4*)(xr + kc0 * 8))[1];                               \
        xvb0 = ((const f32x4*)(xr + kc1 * 8))[0];                               \
        xvb1 = ((const f32x4*)(xr + kc1 * 8))[1];                               \
        mkst = mask[(size_t)gb_s * T_ + ts];                                    \
      }                                                                         \
    }                                                                           \
    {                                                                           \
      const char* hsP = (const char*)HS[PAR];                                   \
      _Pragma("unroll") for (int kp = 0; kp < 4; ++kp) {                        \
        short8 b0 = *(const short8*)(hsP + ro[2 * kp]);                         \
        short8 b1 = *(const short8*)(hsP + ro[2 * kp + 1]);                     \
        _Pragma("unroll") for (int i = 0; i < 4; ++i) {                         \
          acc[i] = mfma16(wh[i][2 * kp], b0, acc[i]);                           \
          acc[i] = mfma16(wh[i][2 * kp + 1], b1, acc[i]);                       \
        }                                                                       \
      }                                                                         \
    }                                                                           \
    float h0 = lstm_ew(acc[0][0], acc[0][1], acc[0][2], acc[0][3], cs[0]);      \
    float h1 = lstm_ew(acc[1][0], acc[1][1], acc[1][2], acc[1][3], cs[1]);      \
    float h2 = lstm_ew(acc[2][0], acc[2][1], acc[2][2], acc[2][3], cs[2]);      \
    float h3 = lstm_ew(acc[3][0], acc[3][1], acc[3][2], acc[3][3], cs[3]);      \
    hsums[0] += h0; hsums[1] += h1; hsums[2] += h2; hsums[3] += h3;             \
    if (more_) {                                                                \
      const unsigned tag = (unsigned)((TT) + 1);                                \
      unsigned long long* __restrict__ hb = (PAR) ? Hb0 : Hb1;                  \
      unsigned pay0, pay1;                                                      \
      asm("v_cvt_pk_bf16_f32 %0, %1, %2" : "=v"(pay0) : "v"(h0), "v"(h1));      \
      asm("v_cvt_pk_bf16_f32 %0, %1, %2" : "=v"(pay1) : "v"(h2), "v"(h3));      \
      unsigned long long w0 = (((unsigned long long)tag) << 32) | (unsigned long long)pay0; \
      unsigned long long w1 = (((unsigned long long)tag) << 32) | (unsigned long long)pay1; \
      __hip_atomic_store(&hb[pub0], w0, __ATOMIC_RELAXED, __HIP_MEMORY_SCOPE_AGENT); \
      __hip_atomic_store(&hb[pub1], w1, __ATOMIC_RELAXED, __HIP_MEMORY_SCOPE_AGENT); \
      asm volatile("" ::: "memory");                                            \
      *(int2*)((char*)HS[1 - (PAR)] + ownOff) = (int2){(int)pay0, (int)pay1};   \
      if constexpr (!PREP) {                                                    \
        short8* xsw = (short8*)XS[1 - (PAR)];                                   \
        xsw[st_r * 32 + ((st_s0 + st_r) & 31)] = cvt8(xva0 * mkst, xva1 * mkst); \
        xsw[st_r * 32 + ((st_s1 + st_r) & 31)] = cvt8(xvb0 * mkst, xvb1 * mkst); \
        bar_lds();                                                              \
      }                                                                         \
      _Pragma("unroll") for (int i = 0; i < 4; ++i) acc[i] = bias4[i];          \
      {                                                                         \
        const char* xsP = (const char*)XS[1 - (PAR)];                           \
        _Pragma("unroll") for (int kp = 0; kp < 4; ++kp) {                      \
          short8 b0 = *(const short8*)(xsP + ro[2 * kp]);                       \
          short8 b1 = *(const short8*)(xsP + ro[2 * kp + 1]);                   \
          _Pragma("unroll") for (int i = 0; i < 4; ++i) {                       \
            acc[i] = mfma16(wi[i][2 * kp], b0, acc[i]);                         \
            acc[i] = mfma16(wi[i][2 * kp + 1], b1, acc[i]);                     \
          }                                                                     \
        }                                                                       \
      }                                                                         \
      unsigned long long v0 = __hip_atomic_load(&hb[p0], __ATOMIC_RELAXED, __HIP_MEMORY_SCOPE_AGENT); \
      unsigned long long v1 = __hip_atomic_load(&hb[p1], __ATOMIC_RELAXED, __HIP_MEMORY_SCOPE_AGENT); \
      unsigned long long v2 = __hip_atomic_load(&hb[p2], __ATOMIC_RELAXED, __HIP_MEMORY_SCOPE_AGENT); \
      unsigned long long v3 = __hip_atomic_load(&hb[p3], __ATOMIC_RELAXED, __HIP_MEMORY_SCOPE_AGENT); \
      unsigned long long v4 = __hip_atomic_load(&hb[p4], __ATOMIC_RELAXED, __HIP_MEMORY_SCOPE_AGENT); \
      unsigned long long v5 = __hip_atomic_load(&hb[p5], __ATOMIC_RELAXED, __HIP_MEMORY_SCOPE_AGENT); \
      asm volatile("" ::: "memory");                                            \
      while (((unsigned)(v0 >> 32) != tag) | ((unsigned)(v1 >> 32) != tag) |    \
             ((unsigned)(v2 >> 32) != tag) | ((unsigned)(v3 >> 32) != tag) |    \
             ((unsigned)(v4 >> 32) != tag) | ((unsigned)(v5 >> 32) != tag)) {   \
        if ((unsigned)(v0 >> 32) != tag)                                        \
          v0 = __hip_atomic_load(&hb[p0], __ATOMIC_RELAXED, __HIP_MEMORY_SCOPE_AGENT); \
        if ((unsigned)(v1 >> 32) != tag)                                        \
          v1 = __hip_atomic_load(&hb[p1], __ATOMIC_RELAXED, __HIP_MEMORY_SCOPE_AGENT); \
        if ((unsigned)(v2 >> 32) != tag)                                        \
          v2 = __hip_atomic_load(&hb[p2], __ATOMIC_RELAXED, __HIP_MEMORY_SCOPE_AGENT); \
        if ((unsigned)(v3 >> 32) != tag)                                        \
          v3 = __hip_atomic_load(&hb[p3], __ATOMIC_RELAXED, __HIP_MEMORY_SCOPE_AGENT); \
        if ((unsigned)(v4 >> 32) != tag)                                        \
          v4 = __hip_atomic_load(&hb[p4], __ATOMIC_RELAXED, __HIP_MEMORY_SCOPE_AGENT); \
        if ((unsigned)(v5 >> 32) != tag)                                        \
          v5 = __hip_atomic_load(&hb[p5], __ATOMIC_RELAXED, __HIP_MEMORY_SCOPE_AGENT); \
        asm volatile("" ::: "memory");                                          \
      }                                                                         \
      char* hw = (char*)HS[1 - (PAR)];                                          \
      *(int*)(hw + uo0) = (int)(unsigned)v0;                                    \
      *(int*)(hw + uo1) = (int)(unsigned)v1;                                    \
      *(int*)(hw + uo2) = (int)(unsigned)v2;                                    \
      *(int*)(hw + uo3) = (int)(unsigned)v3;                                    \
      *(int*)(hw + uo4) = (int)(unsigned)v4;                                    \
      *(int*)(hw + uo5) = (int)(unsigned)v5;                                    \
      bar_lds();                                                                \
    }                                                                           \
  }

// ---------------- rec: fused projection + recurrence --------------------------
// grid 64 x 256 threads (4 waves, 1 wave/SIMD, 512-VGPR budget).
// g = bid & 15, m = bid >> 4. Member m owns units [m*64, m*64+64).
// Row permutation sigma: tile T = 4w+i, A-row l15 -> gate l15&3,
//   unit = 16w + 4*(l15>>2) + i;  D-side: acc[i][r] = gate r of unit 16w+4*l4+i.
template <bool PREP>
__global__ __launch_bounds__(256, 1) void rec_kernel(
    const float* __restrict__ x, const float* __restrict__ mask,
    const unsigned short* __restrict__ img,
    const float* __restrict__ WihF, const float* __restrict__ WhhF,
    const float* __restrict__ bF, const float* __restrict__ WihB,
    const float* __restrict__ WhhB, const float* __restrict__ bB,
    unsigned long long* __restrict__ Hbuf, float* __restrict__ hsum) {
  __shared__ __align__(16) short XS[2][16 * 256];  // x stage, parity dbuf (16KB)
  __shared__ __align__(16) short HS[2][16 * 256];  // h stage, parity dbuf (16KB)

  const int bid = blockIdx.x;
  const int g = bid & 15, m = bid >> 4;
  const int d = g >> 3, bblk = g & 7;
  const int tid = threadIdx.x;
  const int w = tid >> 6, l = tid & 63, l15 = l & 15, l4 = l >> 4;

  // fallback staging: thread covers slots (tid*2, tid*2+1) of row tid>>4
  const int st_r = tid >> 4, st_s0 = (tid * 2) & 31, st_s1 = st_s0 + 1;
  const int kc0 = (st_s0 - st_r) & 31, kc1 = (st_s1 - st_r) & 31;
  const int gb_s = bblk * 16 + st_r;

  const float* Wih = d ? WihB : WihF;
  const float* Whh = d ? WhhB : WhhF;
  const float* bias = d ? bB : bF;

  // ---- weight A-fragments -> registers (4 tiles/wave) ----
  short8 wi[4][8], wh[4][8];
#pragma unroll
  for (int i = 0; i < 4; ++i) {
    size_t nat = (size_t)((l15 & 3) * 256 + m * 64 + 16 * w + 4 * (l15 >> 2) + i);
#pragma unroll
    for (int kb = 0; kb < 8; ++kb) {
      const f32x4* pi = (const f32x4*)(Wih + nat * E_ + kb * 32 + l4 * 8);
      wi[i][kb] = cvt8(pi[0], pi[1]);
      const f32x4* ph = (const f32x4*)(Whh + nat * H_ + kb * 32 + l4 * 8);
      wh[i][kb] = cvt8(ph[0], ph[1]);
    }
  }
  f32x4 bias4[4];
#pragma unroll
  for (int i = 0; i < 4; ++i)
#pragma unroll
    for (int r = 0; r < 4; ++r)
      bias4[i][r] = bias[r * 256 + m * 64 + 16 * w + 4 * l4 + i];

  // ---- precomputed lane constants ----
  // B-operand byte offsets (rotation swizzle): row l15, chunk c -> l15*512+((c+l15)&31)*16
  int ro[8];
#pragma unroll
  for (int kp = 0; kp < 4; ++kp) {
    ro[2 * kp] = l15 * 512 + ((((kp * 8 + l4) + l15) & 31) << 4);
    ro[2 * kp + 1] = l15 * 512 + ((((kp * 8 + 4 + l4) + l15) & 31) << 4);
  }
  // publish words: widx = m*512 + w*128 + j*64 + l4*16 + l15 (contiguous per store)
  const int pub0 = m * 512 + w * 128 + l4 * 16 + l15;
  const int pub1 = pub0 + 64;
  // own HS: units 16w+4*l4+{0..3} -> chunk m*8+2w+(l4>>1), bytes 8*(l4&1)..+7 (b64)
  const int ownOff =
      l15 * 512 + ((((m * 8 + 2 * w + (l4 >> 1)) + l15) & 31) << 4) + 8 * (l4 & 1);
  // poll: 6 words/thread, skip own member's 512-block
  const int pp = tid * 6;
  const int p0 = pp + (pp >= m * 512 ? 512 : 0);
  const int p1 = pp + 1 + (pp + 1 >= m * 512 ? 512 : 0);
  const int p2 = pp + 2 + (pp + 2 >= m * 512 ? 512 : 0);
  const int p3 = pp + 3 + (pp + 3 >= m * 512 ? 512 : 0);
  const int p4 = pp + 4 + (pp + 4 >= m * 512 ? 512 : 0);
  const int p5 = pp + 5 + (pp + 5 >= m * 512 ? 512 : 0);
  // unpack byte offsets: widx p -> (mm=p>>9, w_=(p>>7)&3, j=(p>>6)&1, l4_=(p>>4)&3, b=p&15)
#define UOFF(p)                                                                  \
  (((p) & 15) * 512 +                                                            \
   (((((p) >> 9) * 8 + 2 * (((p) >> 7) & 3) + ((((p) >> 4) & 3) >> 1)) +         \
     ((p) & 15)) & 31) * 16 +                                                    \
   8 * ((((p) >> 4) & 3) & 1) + 4 * (((p) >> 6) & 1))
  const int uo0 = UOFF(p0), uo1 = UOFF(p1), uo2 = UOFF(p2);
  const int uo3 = UOFF(p3), uo4 = UOFF(p4), uo5 = UOFF(p5);
#undef UOFF
  // Hbuf parity bases
  unsigned long long* __restrict__ Hb0 = Hbuf + ((size_t)g * 2 + 0) * 2048;
  unsigned long long* __restrict__ Hb1 = Hbuf + ((size_t)g * 2 + 1) * 2048;

  // x image source pointer; one 8KB tile per t (thread covers 2x16B, 4KB apart)
  const int dstep = d ? -8192 : 8192;
  const char* gsrc = (const char*)img +
      ((size_t)(bblk * 1024 + (d ? (T_ - 1) : 0)) * 8192) + (size_t)tid * 16;

  // ---- prologue: HS[0]=0; stage x_0 and x_1; acc = bias + xg_0 ----
  ((int4*)HS)[tid] = (int4){0, 0, 0, 0};
  ((int4*)HS)[tid + 256] = (int4){0, 0, 0, 0};
  if constexpr (PREP) {
    gload16(gsrc, (char*)XS[0] + w * 1024);
    gload16(gsrc + 4096, (char*)XS[0] + 4096 + w * 1024);
    gload16(gsrc + dstep, (char*)XS[1] + w * 1024);
    gload16(gsrc + dstep + 4096, (char*)XS[1] + 4096 + w * 1024);
    gsrc += 2 * dstep;
  } else {
    int ts = d ? (T_ - 1) : 0;
    const float* xr = x + ((size_t)gb_s * T_ + ts) * E_;
    float mk = mask[(size_t)gb_s * T_ + ts];
    f32x4 a0 = ((const f32x4*)(xr + kc0 * 8))[0] * mk;
    f32x4 a1 = ((const f32x4*)(xr + kc0 * 8))[1] * mk;
    f32x4 b0 = ((const f32x4*)(xr + kc1 * 8))[0] * mk;
    f32x4 b1 = ((const f32x4*)(xr + kc1 * 8))[1] * mk;
    ((short8*)XS[0])[st_r * 32 + ((st_s0 + st_r) & 31)] = cvt8(a0, a1);
    ((short8*)XS[0])[st_r * 32 + ((st_s1 + st_r) & 31)] = cvt8(b0, b1);
  }
  __syncthreads();  // drains gloads + HS[0] zeros visible

  f32x4 acc[4];
#pragma unroll
  for (int i = 0; i < 4; ++i) acc[i] = bias4[i];
  {
    const char* xsP = (const char*)XS[0];
#pragma unroll
    for (int kp = 0; kp < 4; ++kp) {
      short8 b0 = *(const short8*)(xsP + ro[2 * kp]);
      short8 b1 = *(const short8*)(xsP + ro[2 * kp + 1]);
#pragma unroll
      for (int i = 0; i < 4; ++i) {
        acc[i] = mfma16(wi[i][2 * kp], b0, acc[i]);
        acc[i] = mfma16(wi[i][2 * kp + 1], b1, acc[i]);
      }
    }
  }
  __syncthreads();  // XS[0] consumed before first in-loop gload overwrites it

  float cs[4] = {0.f, 0.f, 0.f, 0.f};
  float hsums[4] = {0.f, 0.f, 0.f, 0.f};

  for (int t2 = 0; t2 < 511; ++t2) {
    const int tt = t2 * 2;
    REC_STEP(0, tt, true);
    REC_STEP(1, tt + 1, true);
  }
  REC_STEP(0, 1022, true);
  REC_STEP(1, 1023, false);

  // pooled sums: lane owns batch bblk*16+l15, units m*64+16w+4*l4+{0..3} (16B store)
  {
    int gb_t = bblk * 16 + l15;
    int gu = m * 64 + 16 * w + 4 * l4;
    *(f32x4*)(hsum + ((size_t)d * B_ + gb_t) * H_ + gu) =
        (f32x4){hsums[0], hsums[1], hsums[2], hsums[3]};
  }
}

// ---------------- head: linear ----------------------------------------------
__global__ __launch_bounds__(256, 1) void head_kernel(
    const float* __restrict__ hsum, const float* __restrict__ Wlin,
    const float* __restrict__ blin, float* __restrict__ out) {
  int tid = threadIdx.x;  // 256 = 128 b x 2 c
  int b = tid >> 1, c = tid & 1;
  const f32x4* hf = (const f32x4*)(hsum + (size_t)b * H_);
  const f32x4* hbk = (const f32x4*)(hsum + (size_t)B_ * H_ + (size_t)b * H_);
  const f32x4* wl = (const f32x4*)(Wlin + (size_t)c * 512);
  float s = 0.f;
  for (int j = 0; j < 64; ++j) {
    f32x4 a = hf[j], ww = wl[j];
    s += a[0] * ww[0] + a[1] * ww[1] + a[2] * ww[2] + a[3] * ww[3];
  }
  for (int j = 0; j < 64; ++j) {
    f32x4 a = hbk[j], ww = wl[64 + j];
    s += a[0] * ww[0] + a[1] * ww[1] + a[2] * ww[2] + a[3] * ww[3];
  }
  out[tid] = s * (1.0f / 1024.0f) + blin[c];
}

// ---------------- launch -----------------------------------------------------
extern "C" void kernel_launch(void* const* d_in, const int* in_sizes, int n_in,
                              void* d_out, int out_size, void* d_ws, size_t ws_size,
                              hipStream_t stream) {
  const float* emb = (const float*)d_in[0];
  const float* mask = (const float*)d_in[1];
  const float* Wih_f = (const float*)d_in[2];
  const float* Whh_f = (const float*)d_in[3];
  const float* b_f = (const float*)d_in[4];
  const float* Wih_b = (const float*)d_in[5];
  const float* Whh_b = (const float*)d_in[6];
  const float* b_b = (const float*)d_in[7];
  const float* Wlin = (const float*)d_in[8];
  const float* blin = (const float*)d_in[9];
  float* out = (float*)d_out;

  const size_t HBUF_BYTES = (size_t)16 * 2 * 2048 * 8;      // 512 KiB
  const size_t HSUM_BYTES = (size_t)2 * B_ * H_ * 4;        // 256 KiB
  const size_t IMG_BYTES = (size_t)8 * 1024 * 512 * 16;     // 64 MiB
  if (ws_size < HBUF_BYTES + HSUM_BYTES) return;
  const bool prep = ws_size >= HBUF_BYTES + HSUM_BYTES + IMG_BYTES;

  char* ws = (char*)d_ws;
  unsigned long long* Hbuf = (unsigned long long*)ws;
  float* hsum = (float*)(ws + HBUF_BYTES);
  unsigned short* img = (unsigned short*)(ws + HBUF_BYTES + HSUM_BYTES);

  (void)hipMemsetAsync(Hbuf, 0, HBUF_BYTES, stream);  // tags start at 1; replay-safe
  if (prep) {
    prep_kernel<<<16384, 256, 0, stream>>>(emb, mask, img);
    rec_kernel<true><<<64, 256, 0, stream>>>(emb, mask, img, Wih_f, Whh_f, b_f,
                                             Wih_b, Whh_b, b_b, Hbuf, hsum);
  } else {
    rec_kernel<false><<<64, 256, 0, stream>>>(emb, mask, img, Wih_f, Whh_f, b_f,
                                              Wih_b, Whh_b, b_b, Hbuf, hsum);
  }
  head_kernel<<<1, 256, 0, stream>>>(hsum, Wlin, blin, out);
}